// Round 11
// baseline (203.925 us; speedup 1.0000x reference)
//
#include <hip/hip_runtime.h>

#define PP 399
#define BB 256

// ===========================================================================
// Fused stage1+stage2 conv+relu+maxpool, group-of-3 pooling:
//   A1_k = max(c1[3k], c1[3k+1], c1[3k+2])
//   e[I] = relu(max(A1_I, A1_{I+1}, A1_{I+2}, c1[3(I+3)]))        (s1 pooled)
//   A2_m = max(c2[3m..3m+2]),  h2[J] = relu(max(A2_J,A2_{J+1},A2_{J+2},c2[3(J+3)]))
// Pipeline per group k: 3 s1-convs -> A1_k ; emit e[k-3]; e feeds s2 FIFO;
// c2 at t2=k-5; s2 pool phase is compile-time per unrolled sub-iteration.
// 6-way T-segmentation via template<SEG>, j0 in {0,7,13,19,25,31}; all mid
// segments share phase constants since k0=3j0-2 == 1 (mod 3).
// All state arrays statically indexed (rule #20). h2 layout: [B][37][3][PP].
// ===========================================================================

template<int SEG>
__device__ __forceinline__ float xload(const float* __restrict__ inp, int idx) {
    if (SEG == 5) {
        int ic = idx < 364 ? idx : 364;          // clamped addr stays in-bounds
        float v = inp[(long)ic * PP];
        return (idx <= 364) ? v : 0.f;           // uniform condition
    }
    return inp[(long)idx * PP];
}

// one s1 group: convs at taus using xv[OFF..OFF+6]; returns A1 and first conv c0
template<int OFF>
__device__ __forceinline__ void s1_group(const float (&xv)[13],
    const float (&w1)[3][5], const float (&B1)[3],
    float (&A1)[3], float (&c0)[3])
{
#pragma unroll
    for (int co = 0; co < 3; ++co) {
        float a0 = B1[co], a1 = B1[co], a2 = B1[co];
#pragma unroll
        for (int t = 0; t < 5; ++t) {
            a0 = fmaf(xv[OFF + t],     w1[co][t], a0);
            a1 = fmaf(xv[OFF + 1 + t], w1[co][t], a1);
            a2 = fmaf(xv[OFF + 2 + t], w1[co][t], a2);
        }
        c0[co] = a0;
        A1[co] = fmaxf(fmaxf(a0, a1), a2);
    }
}

// s2 step: consume one e (newest), optionally compute c2 and pool/emit.
template<int P2>
__device__ __forceinline__ void s2_step(
    float (&fe)[3][4], const float (&e)[3],
    const float (&w2)[3][3][5], const float (&B2)[3],
    float (&A2a)[3], float (&A2b)[3], float (&A2c)[3], float (&A2cur)[3],
    float*& op, bool do_c2, bool do_emit)
{
    if (do_c2) {
        float c2v[3];
#pragma unroll
        for (int co = 0; co < 3; ++co) {
            float a = B2[co];
#pragma unroll
            for (int ci = 0; ci < 3; ++ci) {
                a = fmaf(fe[ci][0], w2[co][ci][0], a);
                a = fmaf(fe[ci][1], w2[co][ci][1], a);
                a = fmaf(fe[ci][2], w2[co][ci][2], a);
                a = fmaf(fe[ci][3], w2[co][ci][3], a);
                a = fmaf(e[ci],     w2[co][ci][4], a);
            }
            c2v[co] = a;
        }
        if (P2 == 0) {
#pragma unroll
            for (int co = 0; co < 3; ++co) { A2a[co] = A2b[co]; A2b[co] = A2c[co]; A2c[co] = A2cur[co]; }
            if (do_emit) {
#pragma unroll
                for (int co = 0; co < 3; ++co)
                    op[co * PP] = fmaxf(fmaxf(fmaxf(fmaxf(A2a[co], A2b[co]), A2c[co]), c2v[co]), 0.f);
                op += 3 * PP;
            }
#pragma unroll
            for (int co = 0; co < 3; ++co) A2cur[co] = c2v[co];
        } else {
#pragma unroll
            for (int co = 0; co < 3; ++co) A2cur[co] = fmaxf(A2cur[co], c2v[co]);
        }
    }
    // FIFO shift (e inserted)
#pragma unroll
    for (int ci = 0; ci < 3; ++ci) {
        fe[ci][0] = fe[ci][1]; fe[ci][1] = fe[ci][2]; fe[ci][2] = fe[ci][3]; fe[ci][3] = e[ci];
    }
}

template<int P2>
__device__ __forceinline__ void emit_e(
    const float (&Aa)[3], const float (&Ab)[3], const float (&Ac)[3],
    const float (&c0)[3],
    float (&fe)[3][4],
    const float (&w2)[3][3][5], const float (&B2)[3],
    float (&A2a)[3], float (&A2b)[3], float (&A2c)[3], float (&A2cur)[3],
    float*& op, bool do_c2, bool do_emit)
{
    float e[3];
#pragma unroll
    for (int co = 0; co < 3; ++co)
        e[co] = fmaxf(fmaxf(fmaxf(fmaxf(Aa[co], Ab[co]), Ac[co]), c0[co]), 0.f);
    s2_step<P2>(fe, e, w2, B2, A2a, A2b, A2c, A2cur, op, do_c2, do_emit);
}

template<int SEG>
__device__ __forceinline__ void s12_body(
    const float* __restrict__ x,
    const float* __restrict__ W1, const float* __restrict__ b1,
    const float* __restrict__ W2, const float* __restrict__ b2,
    float* __restrict__ h2, int b, int p)
{
    constexpr int J0tab[7] = {0, 7, 13, 19, 25, 31, 37};
    constexpr int j0 = J0tab[SEG];
    constexpr int j1 = J0tab[SEG + 1];
    constexpr int k0 = (SEG == 0) ? 0 : 3 * j0 - 2;
    constexpr int kend = (3 * j1 + 11 < 121) ? (3 * j1 + 11) : 121;
    constexpr int NGRP = kend - k0 + 1;
    constexpr int NS = NGRP / 3;
    constexpr int NREM = NGRP - 3 * NS;
    constexpr int c2start = (SEG == 0) ? 5 : (k0 + 7);
    constexpr int e2start = 3 * j0 + 14;
    constexpr int P2_0 = (SEG == 0) ? 1 : 2;   // p2 phase of sub-iteration u
    constexpr int P2_1 = (SEG == 0) ? 2 : 0;
    constexpr int P2_2 = (SEG == 0) ? 0 : 1;

    float w1[3][5], B1[3];
    {
        const float* wp = W1 + (long)p * 15;
#pragma unroll
        for (int co = 0; co < 3; ++co) {
#pragma unroll
            for (int t = 0; t < 5; ++t) w1[co][t] = wp[co * 5 + t];
            B1[co] = b1[(long)p * 3 + co];
        }
    }
    float w2[3][3][5], B2[3];
    {
        const float* wp = W2 + (long)p * 45;
#pragma unroll
        for (int co = 0; co < 3; ++co) {
#pragma unroll
            for (int ci = 0; ci < 3; ++ci)
#pragma unroll
                for (int t = 0; t < 5; ++t) w2[co][ci][t] = wp[(co * 3 + ci) * 5 + t];
            B2[co] = b2[(long)p * 3 + co];
        }
    }

    const float* __restrict__ inp = x + (long)b * 365 * PP + p;
    float* op = h2 + ((long)b * 37 + j0) * 3 * PP + p;   // layout [B][37][3][PP]

    // x window regs: xv[s] = x[3k-2+s], covering x[3k-2 .. 3k+10]
    float xv[13];
#pragma unroll
    for (int s = 0; s < 13; ++s) {
        int idx = 3 * k0 - 2 + s;          // SEG0: s<2 -> pad 0
        xv[s] = (idx >= 0) ? inp[(long)idx * PP] : 0.f;
    }

    float fe[3][4];                        // e-FIFO; init = left pad
    float A1p[3][3];                       // prev super's A1 (groups k-3,k-2,k-1)
    float A2a[3], A2b[3], A2c[3], A2cur[3];
#pragma unroll
    for (int ci = 0; ci < 3; ++ci)
#pragma unroll
        for (int s = 0; s < 4; ++s) fe[ci][s] = 0.f;
#pragma unroll
    for (int co = 0; co < 3; ++co) {
        A1p[0][co] = 0.f; A1p[1][co] = 0.f; A1p[2][co] = 0.f;
        A2a[co] = 0.f; A2b[co] = 0.f; A2c[co] = 0.f; A2cur[co] = 0.f;
    }

    for (int S = 0; S < NS; ++S) {
        int k = k0 + 3 * S;
        // prefetch next super's 9 x-values (x[3k+11 .. 3k+19])
        float q[9];
#pragma unroll
        for (int s = 0; s < 9; ++s)
            q[s] = xload<SEG>(inp, 3 * k + 11 + s);

        float A1c0[3], A1c1[3], A1c2[3], c0[3];

        // ---- u = 0 (group k) ----
        s1_group<0>(xv, w1, B1, A1c0, c0);
        if (S >= 1)
            emit_e<P2_0>(A1p[0], A1p[1], A1p[2], c0, fe, w2, B2,
                         A2a, A2b, A2c, A2cur, op,
                         k >= c2start, k >= e2start);
        // ---- u = 1 (group k+1) ----
        s1_group<3>(xv, w1, B1, A1c1, c0);
        if (S >= 1)
            emit_e<P2_1>(A1p[1], A1p[2], A1c0, c0, fe, w2, B2,
                         A2a, A2b, A2c, A2cur, op,
                         k + 1 >= c2start, k + 1 >= e2start);
        // ---- u = 2 (group k+2) ----
        s1_group<6>(xv, w1, B1, A1c2, c0);
        if (S >= 1)
            emit_e<P2_2>(A1p[2], A1c0, A1c1, c0, fe, w2, B2,
                         A2a, A2b, A2c, A2cur, op,
                         k + 2 >= c2start, k + 2 >= e2start);

        // latch
#pragma unroll
        for (int co = 0; co < 3; ++co) {
            A1p[0][co] = A1c0[co]; A1p[1][co] = A1c1[co]; A1p[2][co] = A1c2[co];
        }
        xv[0] = xv[9]; xv[1] = xv[10]; xv[2] = xv[11]; xv[3] = xv[12];
#pragma unroll
        for (int s = 0; s < 9; ++s) xv[4 + s] = q[s];
    }

    // remainder groups (phases continue: u = 0, then 1)
    if constexpr (NREM >= 1) {
        int k = k0 + 3 * NS;
        float A1c0[3], c0[3];
        s1_group<0>(xv, w1, B1, A1c0, c0);
        emit_e<P2_0>(A1p[0], A1p[1], A1p[2], c0, fe, w2, B2,
                     A2a, A2b, A2c, A2cur, op,
                     k >= c2start, k >= e2start);
        if constexpr (NREM >= 2) {
            float A1c1[3];
            s1_group<3>(xv, w1, B1, A1c1, c0);
            emit_e<P2_1>(A1p[1], A1p[2], A1c0, c0, fe, w2, B2,
                         A2a, A2b, A2c, A2cur, op,
                         k + 1 >= c2start, k + 1 >= e2start);
        }
    }
    // last-segment tail: one zero-e feed (e[119]) -> c2[117] -> emit window J=36
    if constexpr (SEG == 5) {
        float ez[3] = {0.f, 0.f, 0.f};
        s2_step<0>(fe, ez, w2, B2, A2a, A2b, A2c, A2cur, op, true, true);
    }
}

__global__ __launch_bounds__(64)
void conv_s12(const float* __restrict__ x,
              const float* __restrict__ W1, const float* __restrict__ b1,
              const float* __restrict__ W2, const float* __restrict__ b2,
              float* __restrict__ h2)
{
    int gid = blockIdx.x * 64 + threadIdx.x;
    if (gid >= BB * PP) return;
    int b = gid / PP;
    int p = gid - b * PP;
    switch (blockIdx.y) {
        case 0: s12_body<0>(x, W1, b1, W2, b2, h2, b, p); break;
        case 1: s12_body<1>(x, W1, b1, W2, b2, h2, b, p); break;
        case 2: s12_body<2>(x, W1, b1, W2, b2, h2, b, p); break;
        case 3: s12_body<3>(x, W1, b1, W2, b2, h2, b, p); break;
        case 4: s12_body<4>(x, W1, b1, W2, b2, h2, b, p); break;
        default: s12_body<5>(x, W1, b1, W2, b2, h2, b, p); break;
    }
}

// ---------------------------------------------------------------------------
// Single-stream stage machine for the small s3+s4 chain.
// ---------------------------------------------------------------------------
template<int CIN>
struct Stage {
    float w[3][CIN][5];
    float b[3];
    float xw[CIN][5];
    float m1[3], m2[3], m3[3];
    int nin;
};

__device__ __forceinline__ void init_s3(Stage<3>& s, const float* __restrict__ Wt,
                                        const float* __restrict__ Bs, int p) {
    const float* wp = Wt + (long)p * 45;
#pragma unroll
    for (int co = 0; co < 3; ++co)
#pragma unroll
        for (int ci = 0; ci < 3; ++ci)
#pragma unroll
            for (int k = 0; k < 5; ++k)
                s.w[co][ci][k] = wp[(co * 3 + ci) * 5 + k];
#pragma unroll
    for (int co = 0; co < 3; ++co) s.b[co] = Bs[(long)p * 3 + co];
#pragma unroll
    for (int ci = 0; ci < 3; ++ci)
#pragma unroll
        for (int k = 0; k < 5; ++k) s.xw[ci][k] = 0.f;
#pragma unroll
    for (int co = 0; co < 3; ++co) { s.m1[co] = -1e30f; s.m2[co] = -1e30f; s.m3[co] = -1e30f; }
    s.nin = 0;
}

template<int CIN>
__device__ __forceinline__ bool feed(Stage<CIN>& s, const float* in, float* out) {
#pragma unroll
    for (int ci = 0; ci < CIN; ++ci) {
        s.xw[ci][0] = s.xw[ci][1];
        s.xw[ci][1] = s.xw[ci][2];
        s.xw[ci][2] = s.xw[ci][3];
        s.xw[ci][3] = s.xw[ci][4];
        s.xw[ci][4] = in[ci];
    }
    int t = s.nin - 2;
    s.nin++;
    if (t < 0) return false;

    float c[3];
#pragma unroll
    for (int co = 0; co < 3; ++co) {
        float a = s.b[co];
#pragma unroll
        for (int ci = 0; ci < CIN; ++ci)
#pragma unroll
            for (int k = 0; k < 5; ++k)
                a = fmaf(s.xw[ci][k], s.w[co][ci][k], a);
        c[co] = fmaxf(a, 0.f);
    }

    bool emit = false;
    int ph = t % 3;
    if (ph == 0) {
        if (t >= 9) {
#pragma unroll
            for (int co = 0; co < 3; ++co) out[co] = fmaxf(s.m1[co], c[co]);
            emit = true;
        }
#pragma unroll
        for (int co = 0; co < 3; ++co) {
            float a = fmaxf(s.m2[co], c[co]);
            float bb = fmaxf(s.m3[co], c[co]);
            s.m1[co] = a; s.m2[co] = bb; s.m3[co] = c[co];
        }
    } else {
#pragma unroll
        for (int co = 0; co < 3; ++co) {
            s.m1[co] = fmaxf(s.m1[co], c[co]);
            s.m2[co] = fmaxf(s.m2[co], c[co]);
            s.m3[co] = fmaxf(s.m3[co], c[co]);
        }
    }
    return emit;
}

// h2 [B][37][3][PP] -> cbuf[b*1297 + co*399 + p]
__global__ __launch_bounds__(64)
void conv_s34(const float* __restrict__ h2,
              const float* __restrict__ W3, const float* __restrict__ b3,
              const float* __restrict__ W4, const float* __restrict__ b4,
              float* __restrict__ cbuf)
{
    int gid = blockIdx.x * 64 + threadIdx.x;
    if (gid >= BB * PP) return;
    int b = gid / PP;
    int p = gid - b * PP;

    Stage<3> s3, s4;
    init_s3(s3, W3, b3, p);
    init_s3(s4, W4, b4, p);

    const float* inp = h2 + (long)b * 37 * 3 * PP + p;
    float* o4 = cbuf + (long)b * 1297 + p;

    float v3[3], v4[3];
    float z[3] = {0.f, 0.f, 0.f};

    float cur[3], nxt[3];
#pragma unroll
    for (int ci = 0; ci < 3; ++ci) {
        cur[ci] = inp[(long)(0 * 3 + ci) * PP];
        nxt[ci] = inp[(long)(1 * 3 + ci) * PP];
    }

    for (int i = 0; i < 39; ++i) {              // 37 real + 2 pads
        float nn[3];
        int i2 = i + 2;
#pragma unroll
        for (int ci = 0; ci < 3; ++ci)
            nn[ci] = (i2 < 37) ? inp[(long)(i2 * 3 + ci) * PP] : 0.f;
        if (feed(s3, cur, v3)) {
            if (feed(s4, v3, v4)) {
#pragma unroll
                for (int co = 0; co < 3; ++co) o4[co * PP] = v4[co];
            }
        }
        cur[0] = nxt[0]; cur[1] = nxt[1]; cur[2] = nxt[2];
        nxt[0] = nn[0];  nxt[1] = nn[1];  nxt[2] = nn[2];
    }
    for (int r = 0; r < 2; ++r) {               // flush s4
        if (feed(s4, z, v4)) {
#pragma unroll
            for (int co = 0; co < 3; ++co) o4[co * PP] = v4[co];
        }
    }
}

// ---------------------------------------------------------------------------
// Split-K GEMM with f32 atomic accumulation. out pre-seeded with bias.
// ---------------------------------------------------------------------------
template<int RELU_A>
__global__ __launch_bounds__(256)
void gemm_atomic(const float* __restrict__ A,
                 const float* __restrict__ Wt,
                 float* __restrict__ out,
                 int K, int N, int lda, int ldo, int kchunk)
{
    __shared__ float As[32][36];
    __shared__ float Bs[32][36];

    int tid = threadIdx.x;
    int ty  = tid >> 3;
    int tx4 = (tid & 7) * 4;
    int c0 = blockIdx.x * 32;
    int m0 = blockIdx.y * 32;
    int k0 = blockIdx.z * kchunk;
    int klim = min(K, k0 + kchunk);

    float4 acc = make_float4(0.f, 0.f, 0.f, 0.f);

    for (int kb = k0; kb < klim; kb += 32) {
#pragma unroll
        for (int j = 0; j < 4; ++j) {
            int kk = kb + tx4 + j;
            float v = (kk < klim) ? A[(long)(m0 + ty) * lda + kk] : 0.f;
            if (RELU_A) v = fmaxf(v, 0.f);
            As[ty][tx4 + j] = v;
        }
#pragma unroll
        for (int j = 0; j < 4; ++j) {
            int kk = kb + ty;
            int c = c0 + tx4 + j;
            Bs[ty][tx4 + j] = (kk < klim && c < N) ? Wt[(long)kk * N + c] : 0.f;
        }
        __syncthreads();
#pragma unroll
        for (int kk = 0; kk < 32; ++kk) {
            float a = As[ty][kk];
            float4 bv = *(const float4*)&Bs[kk][tx4];
            acc.x = fmaf(a, bv.x, acc.x);
            acc.y = fmaf(a, bv.y, acc.y);
            acc.z = fmaf(a, bv.z, acc.z);
            acc.w = fmaf(a, bv.w, acc.w);
        }
        __syncthreads();
    }

    long m = m0 + ty;
    if (c0 + tx4 + 0 < N) atomicAdd(&out[m * ldo + c0 + tx4 + 0], acc.x);
    if (c0 + tx4 + 1 < N) atomicAdd(&out[m * ldo + c0 + tx4 + 1], acc.y);
    if (c0 + tx4 + 2 < N) atomicAdd(&out[m * ldo + c0 + tx4 + 2], acc.z);
    if (c0 + tx4 + 3 < N) atomicAdd(&out[m * ldo + c0 + tx4 + 3], acc.w);
}

__global__ __launch_bounds__(256)
void init_bias(float* __restrict__ e1, const float* __restrict__ lb1,
               float* __restrict__ e2, const float* __restrict__ lb2,
               float* __restrict__ enc2, const float* __restrict__ lb3,
               float* __restrict__ c1, const float* __restrict__ cb1,
               float* __restrict__ c2, const float* __restrict__ cb2,
               float* __restrict__ c3, const float* __restrict__ cb3)
{
    int idx = blockIdx.x * 256 + threadIdx.x;
    if (idx < BB * 700) { e1[idx] = lb1[idx % 700]; return; }
    idx -= BB * 700;
    if (idx < BB * 200) { e2[idx] = lb2[idx % 200]; return; }
    idx -= BB * 200;
    if (idx < BB * 100) { int m = idx / 100, c = idx % 100; enc2[(long)m * 1297 + c] = lb3[c]; return; }
    idx -= BB * 100;
    if (idx < BB * 500) { c1[idx] = cb1[idx % 500]; return; }
    idx -= BB * 500;
    if (idx < BB * 100) { c2[idx] = cb2[idx % 100]; return; }
    idx -= BB * 100;
    if (idx < BB * 20)  { c3[idx] = cb3[idx % 20]; return; }
}

__global__ __launch_bounds__(64)
void final_kernel(const float* __restrict__ c3,
                  const float* __restrict__ fW,
                  const float* __restrict__ fb,
                  float* __restrict__ out)
{
    int m = blockIdx.x * 64 + threadIdx.x;
    if (m >= BB) return;
    float acc = fb[0];
#pragma unroll
    for (int k = 0; k < 20; ++k)
        acc = fmaf(fmaxf(c3[m * 20 + k], 0.f), fW[k], acc);
    out[m] = acc;
}

extern "C" void kernel_launch(void* const* d_in, const int* in_sizes, int n_in,
                              void* d_out, int out_size, void* d_ws, size_t ws_size,
                              hipStream_t stream)
{
    const float* x   = (const float*)d_in[0];
    const float* x2  = (const float*)d_in[1];
    const float* W1  = (const float*)d_in[2];
    const float* b1  = (const float*)d_in[3];
    const float* W2  = (const float*)d_in[4];
    const float* b2  = (const float*)d_in[5];
    const float* W3  = (const float*)d_in[6];
    const float* b3  = (const float*)d_in[7];
    const float* W4  = (const float*)d_in[8];
    const float* b4  = (const float*)d_in[9];
    const float* lW1 = (const float*)d_in[10];
    const float* lb1 = (const float*)d_in[11];
    const float* lW2 = (const float*)d_in[12];
    const float* lb2 = (const float*)d_in[13];
    const float* lW3 = (const float*)d_in[14];
    const float* lb3 = (const float*)d_in[15];
    const float* cW1 = (const float*)d_in[16];
    const float* cb1 = (const float*)d_in[17];
    const float* cW2 = (const float*)d_in[18];
    const float* cb2 = (const float*)d_in[19];
    const float* cW3 = (const float*)d_in[20];
    const float* cb3 = (const float*)d_in[21];
    const float* fW  = (const float*)d_in[22];
    const float* fb  = (const float*)d_in[23];
    float* out = (float*)d_out;

    float* ws = (float*)d_ws;
    const long n_h2   = (long)BB * 37 * 3 * PP;
    const long n_cbuf = (long)BB * 1297;
    float* h2   = ws;
    float* cbuf = h2 + n_h2;
    float* e1   = cbuf + n_cbuf;
    float* e2   = e1 + (long)BB * 700;
    float* c1   = e2 + (long)BB * 200;
    float* c2   = c1 + (long)BB * 500;
    float* c3b  = c2 + (long)BB * 100;

    init_bias<<<1620, 256, 0, stream>>>(e1, lb1, e2, lb2, cbuf + 1197, lb3,
                                        c1, cb1, c2, cb2, c3b, cb3);

    // fused conv chains: one dispatch, 6 segments via blockIdx.y
    conv_s12<<<dim3(1596, 6), 64, 0, stream>>>(x, W1, b1, W2, b2, h2);
    conv_s34<<<1596, 64, 0, stream>>>(h2, W3, b3, W4, b4, cbuf);

    // enc2 path (ReLU applied on consumer's A-load)
    gemm_atomic<0><<<dim3(22, 8, 6), 256, 0, stream>>>(x2, lW1, e1, 1307, 700, 1307, 700, 256);
    gemm_atomic<1><<<dim3( 7, 8, 6), 256, 0, stream>>>(e1, lW2, e2,  700, 200,  700, 200, 128);
    gemm_atomic<1><<<dim3( 4, 8, 4), 256, 0, stream>>>(e2, lW3, cbuf + 1197, 200, 100, 200, 1297, 64);

    // combined head
    gemm_atomic<0><<<dim3(16, 8, 6), 256, 0, stream>>>(cbuf, cW1, c1, 1297, 500, 1297, 500, 256);
    gemm_atomic<1><<<dim3( 4, 8, 8), 256, 0, stream>>>(c1, cW2, c2, 500, 100, 500, 100, 64);
    gemm_atomic<1><<<dim3( 1, 8, 4), 256, 0, stream>>>(c2, cW3, c3b, 100, 20, 100, 20, 32);

    final_kernel<<<dim3(4), 64, 0, stream>>>(c3b, fW, fb, out);
}

// Round 12
// 199.628 us; speedup vs baseline: 1.0215x; 1.0215x over previous
//
#include <hip/hip_runtime.h>

#define PP 399
#define BB 256

// ===========================================================================
// Fused stage1+stage2 conv+relu+maxpool, group-of-3 pooling:
//   A1_k = max(c1[3k..3k+2]);  e[I] = relu(max(A1_I,A1_{I+1},A1_{I+2},c1[3(I+3)]))
//   A2_m = max(c2[3m..3m+2]);  h2[J] = relu(max(A2_J,A2_{J+1},A2_{J+2},c2[3(J+3)]))
// Pipeline per group k: 3 s1-convs -> A1_k ; emit e[k-3]; e feeds s2 FIFO;
// c2 at t2=k-5; s2 pool phase compile-time per unrolled sub-iteration.
// 3-way T-segmentation via template<SEG> (j0 in {0,13,25}).
// 2-super-deep load prefetch: q2 (super S+2) issued while computing super S.
// All state arrays statically indexed (rule #20). h2 layout: [B][37][3][PP].
// ===========================================================================

template<int SEG>
__device__ __forceinline__ float xload(const float* __restrict__ inp, int idx) {
    if (SEG == 2) {
        int ic = idx < 364 ? idx : 364;          // clamped addr stays in-bounds
        float v = inp[(long)ic * PP];
        return (idx <= 364) ? v : 0.f;           // uniform condition
    }
    return inp[(long)idx * PP];
}

// one s1 group: convs at taus using xv[OFF..OFF+6]; returns A1 and first conv c0
template<int OFF>
__device__ __forceinline__ void s1_group(const float (&xv)[13],
    const float (&w1)[3][5], const float (&B1)[3],
    float (&A1)[3], float (&c0)[3])
{
#pragma unroll
    for (int co = 0; co < 3; ++co) {
        float a0 = B1[co], a1 = B1[co], a2 = B1[co];
#pragma unroll
        for (int t = 0; t < 5; ++t) {
            a0 = fmaf(xv[OFF + t],     w1[co][t], a0);
            a1 = fmaf(xv[OFF + 1 + t], w1[co][t], a1);
            a2 = fmaf(xv[OFF + 2 + t], w1[co][t], a2);
        }
        c0[co] = a0;
        A1[co] = fmaxf(fmaxf(a0, a1), a2);
    }
}

// s2 step: consume one e (newest), optionally compute c2 and pool/emit.
template<int P2>
__device__ __forceinline__ void s2_step(
    float (&fe)[3][4], const float (&e)[3],
    const float (&w2)[3][3][5], const float (&B2)[3],
    float (&A2a)[3], float (&A2b)[3], float (&A2c)[3], float (&A2cur)[3],
    float*& op, bool do_c2, bool do_emit)
{
    if (do_c2) {
        float c2v[3];
#pragma unroll
        for (int co = 0; co < 3; ++co) {
            float a = B2[co];
#pragma unroll
            for (int ci = 0; ci < 3; ++ci) {
                a = fmaf(fe[ci][0], w2[co][ci][0], a);
                a = fmaf(fe[ci][1], w2[co][ci][1], a);
                a = fmaf(fe[ci][2], w2[co][ci][2], a);
                a = fmaf(fe[ci][3], w2[co][ci][3], a);
                a = fmaf(e[ci],     w2[co][ci][4], a);
            }
            c2v[co] = a;
        }
        if (P2 == 0) {
#pragma unroll
            for (int co = 0; co < 3; ++co) { A2a[co] = A2b[co]; A2b[co] = A2c[co]; A2c[co] = A2cur[co]; }
            if (do_emit) {
#pragma unroll
                for (int co = 0; co < 3; ++co)
                    op[co * PP] = fmaxf(fmaxf(fmaxf(fmaxf(A2a[co], A2b[co]), A2c[co]), c2v[co]), 0.f);
                op += 3 * PP;
            }
#pragma unroll
            for (int co = 0; co < 3; ++co) A2cur[co] = c2v[co];
        } else {
#pragma unroll
            for (int co = 0; co < 3; ++co) A2cur[co] = fmaxf(A2cur[co], c2v[co]);
        }
    }
    // FIFO shift (e inserted)
#pragma unroll
    for (int ci = 0; ci < 3; ++ci) {
        fe[ci][0] = fe[ci][1]; fe[ci][1] = fe[ci][2]; fe[ci][2] = fe[ci][3]; fe[ci][3] = e[ci];
    }
}

template<int P2>
__device__ __forceinline__ void emit_e(
    const float (&Aa)[3], const float (&Ab)[3], const float (&Ac)[3],
    const float (&c0)[3],
    float (&fe)[3][4],
    const float (&w2)[3][3][5], const float (&B2)[3],
    float (&A2a)[3], float (&A2b)[3], float (&A2c)[3], float (&A2cur)[3],
    float*& op, bool do_c2, bool do_emit)
{
    float e[3];
#pragma unroll
    for (int co = 0; co < 3; ++co)
        e[co] = fmaxf(fmaxf(fmaxf(fmaxf(Aa[co], Ab[co]), Ac[co]), c0[co]), 0.f);
    s2_step<P2>(fe, e, w2, B2, A2a, A2b, A2c, A2cur, op, do_c2, do_emit);
}

template<int SEG>
__device__ __forceinline__ void s12_body(
    const float* __restrict__ x,
    const float* __restrict__ W1, const float* __restrict__ b1,
    const float* __restrict__ W2, const float* __restrict__ b2,
    float* __restrict__ h2, int b, int p)
{
    constexpr int J0tab[4] = {0, 13, 25, 37};
    constexpr int j0 = J0tab[SEG];
    constexpr int j1 = J0tab[SEG + 1];
    constexpr int k0 = (SEG == 0) ? 0 : 3 * j0 - 2;                 // 0, 37, 73
    constexpr int kend = (3 * j1 + 11 < 121) ? (3 * j1 + 11) : 121; // 50, 86, 121
    constexpr int NGRP = kend - k0 + 1;                             // 51, 50, 49
    constexpr int NS = NGRP / 3;                                    // 17, 16, 16
    constexpr int NREM = NGRP - 3 * NS;                             // 0, 2, 1
    constexpr int c2start = (SEG == 0) ? 5 : (k0 + 7);
    constexpr int e2start = 3 * j0 + 14;
    constexpr int P2_0 = (SEG == 0) ? 1 : 2;   // p2 phase of sub-iteration u
    constexpr int P2_1 = (SEG == 0) ? 2 : 0;
    constexpr int P2_2 = (SEG == 0) ? 0 : 1;

    float w1[3][5], B1[3];
    {
        const float* wp = W1 + (long)p * 15;
#pragma unroll
        for (int co = 0; co < 3; ++co) {
#pragma unroll
            for (int t = 0; t < 5; ++t) w1[co][t] = wp[co * 5 + t];
            B1[co] = b1[(long)p * 3 + co];
        }
    }
    float w2[3][3][5], B2[3];
    {
        const float* wp = W2 + (long)p * 45;
#pragma unroll
        for (int co = 0; co < 3; ++co) {
#pragma unroll
            for (int ci = 0; ci < 3; ++ci)
#pragma unroll
                for (int t = 0; t < 5; ++t) w2[co][ci][t] = wp[(co * 3 + ci) * 5 + t];
            B2[co] = b2[(long)p * 3 + co];
        }
    }

    const float* __restrict__ inp = x + (long)b * 365 * PP + p;
    float* op = h2 + ((long)b * 37 + j0) * 3 * PP + p;   // layout [B][37][3][PP]

    // prologue: xv = x[3k0-2 .. 3k0+10]; q1 = x[3k0+11 .. 3k0+19] (super S+1)
    float xv[13];
#pragma unroll
    for (int s = 0; s < 13; ++s) {
        int idx = 3 * k0 - 2 + s;          // SEG0: s<2 -> pad 0
        xv[s] = (idx >= 0) ? inp[(long)idx * PP] : 0.f;
    }
    float q1[9];
#pragma unroll
    for (int s = 0; s < 9; ++s)
        q1[s] = xload<SEG>(inp, 3 * k0 + 11 + s);

    float fe[3][4];                        // e-FIFO; init = left pad
    float A1p[3][3];                       // prev super's A1 (groups k-3,k-2,k-1)
    float A2a[3], A2b[3], A2c[3], A2cur[3];
#pragma unroll
    for (int ci = 0; ci < 3; ++ci)
#pragma unroll
        for (int s = 0; s < 4; ++s) fe[ci][s] = 0.f;
#pragma unroll
    for (int co = 0; co < 3; ++co) {
        A1p[0][co] = 0.f; A1p[1][co] = 0.f; A1p[2][co] = 0.f;
        A2a[co] = 0.f; A2b[co] = 0.f; A2c[co] = 0.f; A2cur[co] = 0.f;
    }

    for (int S = 0; S < NS; ++S) {
        int k = k0 + 3 * S;
        // issue loads for super S+2 (x[3k+20 .. 3k+28]) — 2-deep pipeline
        float q2[9];
#pragma unroll
        for (int s = 0; s < 9; ++s)
            q2[s] = xload<SEG>(inp, 3 * k + 20 + s);

        float A1c0[3], A1c1[3], A1c2[3], c0[3];

        // ---- u = 0 (group k) ----
        s1_group<0>(xv, w1, B1, A1c0, c0);
        if (S >= 1)
            emit_e<P2_0>(A1p[0], A1p[1], A1p[2], c0, fe, w2, B2,
                         A2a, A2b, A2c, A2cur, op,
                         k >= c2start, k >= e2start);
        // ---- u = 1 (group k+1) ----
        s1_group<3>(xv, w1, B1, A1c1, c0);
        if (S >= 1)
            emit_e<P2_1>(A1p[1], A1p[2], A1c0, c0, fe, w2, B2,
                         A2a, A2b, A2c, A2cur, op,
                         k + 1 >= c2start, k + 1 >= e2start);
        // ---- u = 2 (group k+2) ----
        s1_group<6>(xv, w1, B1, A1c2, c0);
        if (S >= 1)
            emit_e<P2_2>(A1p[2], A1c0, A1c1, c0, fe, w2, B2,
                         A2a, A2b, A2c, A2cur, op,
                         k + 2 >= c2start, k + 2 >= e2start);

        // latch A1s; rotate x window from q1; q1 <- q2
#pragma unroll
        for (int co = 0; co < 3; ++co) {
            A1p[0][co] = A1c0[co]; A1p[1][co] = A1c1[co]; A1p[2][co] = A1c2[co];
        }
        xv[0] = xv[9]; xv[1] = xv[10]; xv[2] = xv[11]; xv[3] = xv[12];
#pragma unroll
        for (int s = 0; s < 9; ++s) { xv[4 + s] = q1[s]; q1[s] = q2[s]; }
    }

    // remainder groups (phases continue: u = 0, then 1)
    if constexpr (NREM >= 1) {
        int k = k0 + 3 * NS;
        float A1c0[3], c0[3];
        s1_group<0>(xv, w1, B1, A1c0, c0);
        emit_e<P2_0>(A1p[0], A1p[1], A1p[2], c0, fe, w2, B2,
                     A2a, A2b, A2c, A2cur, op,
                     k >= c2start, k >= e2start);
        if constexpr (NREM >= 2) {
            float A1c1[3];
            s1_group<3>(xv, w1, B1, A1c1, c0);
            emit_e<P2_1>(A1p[1], A1p[2], A1c0, c0, fe, w2, B2,
                         A2a, A2b, A2c, A2cur, op,
                         k + 1 >= c2start, k + 1 >= e2start);
        }
    }
    // last-segment tail: one zero-e feed (e[119]) -> c2[117] -> emit window J=36
    if constexpr (SEG == 2) {
        float ez[3] = {0.f, 0.f, 0.f};
        s2_step<0>(fe, ez, w2, B2, A2a, A2b, A2c, A2cur, op, true, true);
    }
}

__global__ __launch_bounds__(64)
void conv_s12(const float* __restrict__ x,
              const float* __restrict__ W1, const float* __restrict__ b1,
              const float* __restrict__ W2, const float* __restrict__ b2,
              float* __restrict__ h2)
{
    int gid = blockIdx.x * 64 + threadIdx.x;
    if (gid >= BB * PP) return;
    int b = gid / PP;
    int p = gid - b * PP;
    if (blockIdx.y == 0)      s12_body<0>(x, W1, b1, W2, b2, h2, b, p);
    else if (blockIdx.y == 1) s12_body<1>(x, W1, b1, W2, b2, h2, b, p);
    else                      s12_body<2>(x, W1, b1, W2, b2, h2, b, p);
}

// ---------------------------------------------------------------------------
// Single-stream stage machine for the small s3+s4 chain.
// ---------------------------------------------------------------------------
template<int CIN>
struct Stage {
    float w[3][CIN][5];
    float b[3];
    float xw[CIN][5];
    float m1[3], m2[3], m3[3];
    int nin;
};

__device__ __forceinline__ void init_s3(Stage<3>& s, const float* __restrict__ Wt,
                                        const float* __restrict__ Bs, int p) {
    const float* wp = Wt + (long)p * 45;
#pragma unroll
    for (int co = 0; co < 3; ++co)
#pragma unroll
        for (int ci = 0; ci < 3; ++ci)
#pragma unroll
            for (int k = 0; k < 5; ++k)
                s.w[co][ci][k] = wp[(co * 3 + ci) * 5 + k];
#pragma unroll
    for (int co = 0; co < 3; ++co) s.b[co] = Bs[(long)p * 3 + co];
#pragma unroll
    for (int ci = 0; ci < 3; ++ci)
#pragma unroll
        for (int k = 0; k < 5; ++k) s.xw[ci][k] = 0.f;
#pragma unroll
    for (int co = 0; co < 3; ++co) { s.m1[co] = -1e30f; s.m2[co] = -1e30f; s.m3[co] = -1e30f; }
    s.nin = 0;
}

template<int CIN>
__device__ __forceinline__ bool feed(Stage<CIN>& s, const float* in, float* out) {
#pragma unroll
    for (int ci = 0; ci < CIN; ++ci) {
        s.xw[ci][0] = s.xw[ci][1];
        s.xw[ci][1] = s.xw[ci][2];
        s.xw[ci][2] = s.xw[ci][3];
        s.xw[ci][3] = s.xw[ci][4];
        s.xw[ci][4] = in[ci];
    }
    int t = s.nin - 2;
    s.nin++;
    if (t < 0) return false;

    float c[3];
#pragma unroll
    for (int co = 0; co < 3; ++co) {
        float a = s.b[co];
#pragma unroll
        for (int ci = 0; ci < CIN; ++ci)
#pragma unroll
            for (int k = 0; k < 5; ++k)
                a = fmaf(s.xw[ci][k], s.w[co][ci][k], a);
        c[co] = fmaxf(a, 0.f);
    }

    bool emit = false;
    int ph = t % 3;
    if (ph == 0) {
        if (t >= 9) {
#pragma unroll
            for (int co = 0; co < 3; ++co) out[co] = fmaxf(s.m1[co], c[co]);
            emit = true;
        }
#pragma unroll
        for (int co = 0; co < 3; ++co) {
            float a = fmaxf(s.m2[co], c[co]);
            float bb = fmaxf(s.m3[co], c[co]);
            s.m1[co] = a; s.m2[co] = bb; s.m3[co] = c[co];
        }
    } else {
#pragma unroll
        for (int co = 0; co < 3; ++co) {
            s.m1[co] = fmaxf(s.m1[co], c[co]);
            s.m2[co] = fmaxf(s.m2[co], c[co]);
            s.m3[co] = fmaxf(s.m3[co], c[co]);
        }
    }
    return emit;
}

// h2 [B][37][3][PP] -> cbuf[b*1297 + co*399 + p]; 5-deep register-ring prefetch
__global__ __launch_bounds__(64)
void conv_s34(const float* __restrict__ h2,
              const float* __restrict__ W3, const float* __restrict__ b3,
              const float* __restrict__ W4, const float* __restrict__ b4,
              float* __restrict__ cbuf)
{
    int gid = blockIdx.x * 64 + threadIdx.x;
    if (gid >= BB * PP) return;
    int b = gid / PP;
    int p = gid - b * PP;

    Stage<3> s3, s4;
    init_s3(s3, W3, b3, p);
    init_s3(s4, W4, b4, p);

    const float* inp = h2 + (long)b * 37 * 3 * PP + p;
    float* o4 = cbuf + (long)b * 1297 + p;

    float v3[3], v4[3];
    float z[3] = {0.f, 0.f, 0.f};

    float r0[3], r1[3], r2[3], r3[3], r4[3];
#pragma unroll
    for (int ci = 0; ci < 3; ++ci) {
        r0[ci] = inp[(long)(0 * 3 + ci) * PP];
        r1[ci] = inp[(long)(1 * 3 + ci) * PP];
        r2[ci] = inp[(long)(2 * 3 + ci) * PP];
        r3[ci] = inp[(long)(3 * 3 + ci) * PP];
        r4[ci] = inp[(long)(4 * 3 + ci) * PP];
    }

    for (int i = 0; i < 39; ++i) {              // 37 real + 2 pads
        float nn[3];
        int i5 = i + 5;
#pragma unroll
        for (int ci = 0; ci < 3; ++ci)
            nn[ci] = (i5 < 37) ? inp[(long)(i5 * 3 + ci) * PP] : 0.f;
        if (feed(s3, r0, v3)) {
            if (feed(s4, v3, v4)) {
#pragma unroll
                for (int co = 0; co < 3; ++co) o4[co * PP] = v4[co];
            }
        }
#pragma unroll
        for (int ci = 0; ci < 3; ++ci) {
            r0[ci] = r1[ci]; r1[ci] = r2[ci]; r2[ci] = r3[ci]; r3[ci] = r4[ci]; r4[ci] = nn[ci];
        }
    }
    for (int r = 0; r < 2; ++r) {               // flush s4
        if (feed(s4, z, v4)) {
#pragma unroll
            for (int co = 0; co < 3; ++co) o4[co * PP] = v4[co];
        }
    }
}

// ---------------------------------------------------------------------------
// Split-K GEMM with f32 atomic accumulation. out pre-seeded with bias.
// ---------------------------------------------------------------------------
template<int RELU_A>
__global__ __launch_bounds__(256)
void gemm_atomic(const float* __restrict__ A,
                 const float* __restrict__ Wt,
                 float* __restrict__ out,
                 int K, int N, int lda, int ldo, int kchunk)
{
    __shared__ float As[32][36];
    __shared__ float Bs[32][36];

    int tid = threadIdx.x;
    int ty  = tid >> 3;
    int tx4 = (tid & 7) * 4;
    int c0 = blockIdx.x * 32;
    int m0 = blockIdx.y * 32;
    int k0 = blockIdx.z * kchunk;
    int klim = min(K, k0 + kchunk);

    float4 acc = make_float4(0.f, 0.f, 0.f, 0.f);

    for (int kb = k0; kb < klim; kb += 32) {
#pragma unroll
        for (int j = 0; j < 4; ++j) {
            int kk = kb + tx4 + j;
            float v = (kk < klim) ? A[(long)(m0 + ty) * lda + kk] : 0.f;
            if (RELU_A) v = fmaxf(v, 0.f);
            As[ty][tx4 + j] = v;
        }
#pragma unroll
        for (int j = 0; j < 4; ++j) {
            int kk = kb + ty;
            int c = c0 + tx4 + j;
            Bs[ty][tx4 + j] = (kk < klim && c < N) ? Wt[(long)kk * N + c] : 0.f;
        }
        __syncthreads();
#pragma unroll
        for (int kk = 0; kk < 32; ++kk) {
            float a = As[ty][kk];
            float4 bv = *(const float4*)&Bs[kk][tx4];
            acc.x = fmaf(a, bv.x, acc.x);
            acc.y = fmaf(a, bv.y, acc.y);
            acc.z = fmaf(a, bv.z, acc.z);
            acc.w = fmaf(a, bv.w, acc.w);
        }
        __syncthreads();
    }

    long m = m0 + ty;
    if (c0 + tx4 + 0 < N) atomicAdd(&out[m * ldo + c0 + tx4 + 0], acc.x);
    if (c0 + tx4 + 1 < N) atomicAdd(&out[m * ldo + c0 + tx4 + 1], acc.y);
    if (c0 + tx4 + 2 < N) atomicAdd(&out[m * ldo + c0 + tx4 + 2], acc.z);
    if (c0 + tx4 + 3 < N) atomicAdd(&out[m * ldo + c0 + tx4 + 3], acc.w);
}

__global__ __launch_bounds__(256)
void init_bias(float* __restrict__ e1, const float* __restrict__ lb1,
               float* __restrict__ e2, const float* __restrict__ lb2,
               float* __restrict__ enc2, const float* __restrict__ lb3,
               float* __restrict__ c1, const float* __restrict__ cb1,
               float* __restrict__ c2, const float* __restrict__ cb2,
               float* __restrict__ c3, const float* __restrict__ cb3)
{
    int idx = blockIdx.x * 256 + threadIdx.x;
    if (idx < BB * 700) { e1[idx] = lb1[idx % 700]; return; }
    idx -= BB * 700;
    if (idx < BB * 200) { e2[idx] = lb2[idx % 200]; return; }
    idx -= BB * 200;
    if (idx < BB * 100) { int m = idx / 100, c = idx % 100; enc2[(long)m * 1297 + c] = lb3[c]; return; }
    idx -= BB * 100;
    if (idx < BB * 500) { c1[idx] = cb1[idx % 500]; return; }
    idx -= BB * 500;
    if (idx < BB * 100) { c2[idx] = cb2[idx % 100]; return; }
    idx -= BB * 100;
    if (idx < BB * 20)  { c3[idx] = cb3[idx % 20]; return; }
}

__global__ __launch_bounds__(64)
void final_kernel(const float* __restrict__ c3,
                  const float* __restrict__ fW,
                  const float* __restrict__ fb,
                  float* __restrict__ out)
{
    int m = blockIdx.x * 64 + threadIdx.x;
    if (m >= BB) return;
    float acc = fb[0];
#pragma unroll
    for (int k = 0; k < 20; ++k)
        acc = fmaf(fmaxf(c3[m * 20 + k], 0.f), fW[k], acc);
    out[m] = acc;
}

extern "C" void kernel_launch(void* const* d_in, const int* in_sizes, int n_in,
                              void* d_out, int out_size, void* d_ws, size_t ws_size,
                              hipStream_t stream)
{
    const float* x   = (const float*)d_in[0];
    const float* x2  = (const float*)d_in[1];
    const float* W1  = (const float*)d_in[2];
    const float* b1  = (const float*)d_in[3];
    const float* W2  = (const float*)d_in[4];
    const float* b2  = (const float*)d_in[5];
    const float* W3  = (const float*)d_in[6];
    const float* b3  = (const float*)d_in[7];
    const float* W4  = (const float*)d_in[8];
    const float* b4  = (const float*)d_in[9];
    const float* lW1 = (const float*)d_in[10];
    const float* lb1 = (const float*)d_in[11];
    const float* lW2 = (const float*)d_in[12];
    const float* lb2 = (const float*)d_in[13];
    const float* lW3 = (const float*)d_in[14];
    const float* lb3 = (const float*)d_in[15];
    const float* cW1 = (const float*)d_in[16];
    const float* cb1 = (const float*)d_in[17];
    const float* cW2 = (const float*)d_in[18];
    const float* cb2 = (const float*)d_in[19];
    const float* cW3 = (const float*)d_in[20];
    const float* cb3 = (const float*)d_in[21];
    const float* fW  = (const float*)d_in[22];
    const float* fb  = (const float*)d_in[23];
    float* out = (float*)d_out;

    float* ws = (float*)d_ws;
    const long n_h2   = (long)BB * 37 * 3 * PP;
    const long n_cbuf = (long)BB * 1297;
    float* h2   = ws;
    float* cbuf = h2 + n_h2;
    float* e1   = cbuf + n_cbuf;
    float* e2   = e1 + (long)BB * 700;
    float* c1   = e2 + (long)BB * 200;
    float* c2   = c1 + (long)BB * 500;
    float* c3b  = c2 + (long)BB * 100;

    init_bias<<<1620, 256, 0, stream>>>(e1, lb1, e2, lb2, cbuf + 1197, lb3,
                                        c1, cb1, c2, cb2, c3b, cb3);

    // fused conv chains: one dispatch, 3 segments via blockIdx.y
    conv_s12<<<dim3(1596, 3), 64, 0, stream>>>(x, W1, b1, W2, b2, h2);
    conv_s34<<<1596, 64, 0, stream>>>(h2, W3, b3, W4, b4, cbuf);

    // enc2 path (ReLU applied on consumer's A-load)
    gemm_atomic<0><<<dim3(22, 8, 6), 256, 0, stream>>>(x2, lW1, e1, 1307, 700, 1307, 700, 256);
    gemm_atomic<1><<<dim3( 7, 8, 6), 256, 0, stream>>>(e1, lW2, e2,  700, 200,  700, 200, 128);
    gemm_atomic<1><<<dim3( 4, 8, 4), 256, 0, stream>>>(e2, lW3, cbuf + 1197, 200, 100, 200, 1297, 64);

    // combined head
    gemm_atomic<0><<<dim3(16, 8, 6), 256, 0, stream>>>(cbuf, cW1, c1, 1297, 500, 1297, 500, 256);
    gemm_atomic<1><<<dim3( 4, 8, 8), 256, 0, stream>>>(c1, cW2, c2, 500, 100, 500, 100, 64);
    gemm_atomic<1><<<dim3( 1, 8, 4), 256, 0, stream>>>(c2, cW3, c3b, 100, 20, 100, 20, 32);

    final_kernel<<<dim3(4), 64, 0, stream>>>(c3b, fW, fb, out);
}

// Round 13
// 161.592 us; speedup vs baseline: 1.2620x; 1.2354x over previous
//
#include <hip/hip_runtime.h>

#define PP 399
#define BB 256

// ===========================================================================
// Fused stage1+stage2 conv+relu+maxpool, group-of-3 pooling (R10 lean body):
//   A1_k = max(c1[3k..3k+2]);  e[I] = relu(max(A1_I,A1_{I+1},A1_{I+2},c1[3(I+3)]))
//   A2_m = max(c2[3m..3m+2]);  h2[J] = relu(max(A2_J,A2_{J+1},A2_{J+2},c2[3(J+3)]))
// 3-way T-segmentation via template<SEG>. Statically indexed state (rule #20).
// h2 layout: [B][37][3][PP].
// This round: 256-thr blocks; conv dispatch co-schedules independent GEMM
// blocks (heterogeneous dispatch) to fill idle issue slots.
// ===========================================================================

template<int SEG>
__device__ __forceinline__ float xload(const float* __restrict__ inp, int idx) {
    if (SEG == 2) {
        int ic = idx < 364 ? idx : 364;
        float v = inp[(long)ic * PP];
        return (idx <= 364) ? v : 0.f;
    }
    return inp[(long)idx * PP];
}

template<int OFF>
__device__ __forceinline__ void s1_group(const float (&xv)[13],
    const float (&w1)[3][5], const float (&B1)[3],
    float (&A1)[3], float (&c0)[3])
{
#pragma unroll
    for (int co = 0; co < 3; ++co) {
        float a0 = B1[co], a1 = B1[co], a2 = B1[co];
#pragma unroll
        for (int t = 0; t < 5; ++t) {
            a0 = fmaf(xv[OFF + t],     w1[co][t], a0);
            a1 = fmaf(xv[OFF + 1 + t], w1[co][t], a1);
            a2 = fmaf(xv[OFF + 2 + t], w1[co][t], a2);
        }
        c0[co] = a0;
        A1[co] = fmaxf(fmaxf(a0, a1), a2);
    }
}

template<int P2>
__device__ __forceinline__ void s2_step(
    float (&fe)[3][4], const float (&e)[3],
    const float (&w2)[3][3][5], const float (&B2)[3],
    float (&A2a)[3], float (&A2b)[3], float (&A2c)[3], float (&A2cur)[3],
    float*& op, bool do_c2, bool do_emit)
{
    if (do_c2) {
        float c2v[3];
#pragma unroll
        for (int co = 0; co < 3; ++co) {
            float a = B2[co];
#pragma unroll
            for (int ci = 0; ci < 3; ++ci) {
                a = fmaf(fe[ci][0], w2[co][ci][0], a);
                a = fmaf(fe[ci][1], w2[co][ci][1], a);
                a = fmaf(fe[ci][2], w2[co][ci][2], a);
                a = fmaf(fe[ci][3], w2[co][ci][3], a);
                a = fmaf(e[ci],     w2[co][ci][4], a);
            }
            c2v[co] = a;
        }
        if (P2 == 0) {
#pragma unroll
            for (int co = 0; co < 3; ++co) { A2a[co] = A2b[co]; A2b[co] = A2c[co]; A2c[co] = A2cur[co]; }
            if (do_emit) {
#pragma unroll
                for (int co = 0; co < 3; ++co)
                    op[co * PP] = fmaxf(fmaxf(fmaxf(fmaxf(A2a[co], A2b[co]), A2c[co]), c2v[co]), 0.f);
                op += 3 * PP;
            }
#pragma unroll
            for (int co = 0; co < 3; ++co) A2cur[co] = c2v[co];
        } else {
#pragma unroll
            for (int co = 0; co < 3; ++co) A2cur[co] = fmaxf(A2cur[co], c2v[co]);
        }
    }
#pragma unroll
    for (int ci = 0; ci < 3; ++ci) {
        fe[ci][0] = fe[ci][1]; fe[ci][1] = fe[ci][2]; fe[ci][2] = fe[ci][3]; fe[ci][3] = e[ci];
    }
}

template<int P2>
__device__ __forceinline__ void emit_e(
    const float (&Aa)[3], const float (&Ab)[3], const float (&Ac)[3],
    const float (&c0)[3],
    float (&fe)[3][4],
    const float (&w2)[3][3][5], const float (&B2)[3],
    float (&A2a)[3], float (&A2b)[3], float (&A2c)[3], float (&A2cur)[3],
    float*& op, bool do_c2, bool do_emit)
{
    float e[3];
#pragma unroll
    for (int co = 0; co < 3; ++co)
        e[co] = fmaxf(fmaxf(fmaxf(fmaxf(Aa[co], Ab[co]), Ac[co]), c0[co]), 0.f);
    s2_step<P2>(fe, e, w2, B2, A2a, A2b, A2c, A2cur, op, do_c2, do_emit);
}

template<int SEG>
__device__ __forceinline__ void s12_body(
    const float* __restrict__ x,
    const float* __restrict__ W1, const float* __restrict__ b1,
    const float* __restrict__ W2, const float* __restrict__ b2,
    float* __restrict__ h2, int b, int p)
{
    constexpr int J0tab[4] = {0, 13, 25, 37};
    constexpr int j0 = J0tab[SEG];
    constexpr int j1 = J0tab[SEG + 1];
    constexpr int k0 = (SEG == 0) ? 0 : 3 * j0 - 2;
    constexpr int kend = (3 * j1 + 11 < 121) ? (3 * j1 + 11) : 121;
    constexpr int NGRP = kend - k0 + 1;
    constexpr int NS = NGRP / 3;
    constexpr int NREM = NGRP - 3 * NS;
    constexpr int c2start = (SEG == 0) ? 5 : (k0 + 7);
    constexpr int e2start = 3 * j0 + 14;
    constexpr int P2_0 = (SEG == 0) ? 1 : 2;
    constexpr int P2_1 = (SEG == 0) ? 2 : 0;
    constexpr int P2_2 = (SEG == 0) ? 0 : 1;

    float w1[3][5], B1[3];
    {
        const float* wp = W1 + (long)p * 15;
#pragma unroll
        for (int co = 0; co < 3; ++co) {
#pragma unroll
            for (int t = 0; t < 5; ++t) w1[co][t] = wp[co * 5 + t];
            B1[co] = b1[(long)p * 3 + co];
        }
    }
    float w2[3][3][5], B2[3];
    {
        const float* wp = W2 + (long)p * 45;
#pragma unroll
        for (int co = 0; co < 3; ++co) {
#pragma unroll
            for (int ci = 0; ci < 3; ++ci)
#pragma unroll
                for (int t = 0; t < 5; ++t) w2[co][ci][t] = wp[(co * 3 + ci) * 5 + t];
            B2[co] = b2[(long)p * 3 + co];
        }
    }

    const float* __restrict__ inp = x + (long)b * 365 * PP + p;
    float* op = h2 + ((long)b * 37 + j0) * 3 * PP + p;

    float xv[13];
#pragma unroll
    for (int s = 0; s < 13; ++s) {
        int idx = 3 * k0 - 2 + s;
        xv[s] = (idx >= 0) ? inp[(long)idx * PP] : 0.f;
    }

    float fe[3][4];
    float A1p[3][3];
    float A2a[3], A2b[3], A2c[3], A2cur[3];
#pragma unroll
    for (int ci = 0; ci < 3; ++ci)
#pragma unroll
        for (int s = 0; s < 4; ++s) fe[ci][s] = 0.f;
#pragma unroll
    for (int co = 0; co < 3; ++co) {
        A1p[0][co] = 0.f; A1p[1][co] = 0.f; A1p[2][co] = 0.f;
        A2a[co] = 0.f; A2b[co] = 0.f; A2c[co] = 0.f; A2cur[co] = 0.f;
    }

    for (int S = 0; S < NS; ++S) {
        int k = k0 + 3 * S;
        float q[9];
#pragma unroll
        for (int s = 0; s < 9; ++s)
            q[s] = xload<SEG>(inp, 3 * k + 11 + s);

        float A1c0[3], A1c1[3], A1c2[3], c0[3];

        s1_group<0>(xv, w1, B1, A1c0, c0);
        if (S >= 1)
            emit_e<P2_0>(A1p[0], A1p[1], A1p[2], c0, fe, w2, B2,
                         A2a, A2b, A2c, A2cur, op,
                         k >= c2start, k >= e2start);
        s1_group<3>(xv, w1, B1, A1c1, c0);
        if (S >= 1)
            emit_e<P2_1>(A1p[1], A1p[2], A1c0, c0, fe, w2, B2,
                         A2a, A2b, A2c, A2cur, op,
                         k + 1 >= c2start, k + 1 >= e2start);
        s1_group<6>(xv, w1, B1, A1c2, c0);
        if (S >= 1)
            emit_e<P2_2>(A1p[2], A1c0, A1c1, c0, fe, w2, B2,
                         A2a, A2b, A2c, A2cur, op,
                         k + 2 >= c2start, k + 2 >= e2start);

#pragma unroll
        for (int co = 0; co < 3; ++co) {
            A1p[0][co] = A1c0[co]; A1p[1][co] = A1c1[co]; A1p[2][co] = A1c2[co];
        }
        xv[0] = xv[9]; xv[1] = xv[10]; xv[2] = xv[11]; xv[3] = xv[12];
#pragma unroll
        for (int s = 0; s < 9; ++s) xv[4 + s] = q[s];
    }

    if constexpr (NREM >= 1) {
        int k = k0 + 3 * NS;
        float A1c0[3], c0[3];
        s1_group<0>(xv, w1, B1, A1c0, c0);
        emit_e<P2_0>(A1p[0], A1p[1], A1p[2], c0, fe, w2, B2,
                     A2a, A2b, A2c, A2cur, op,
                     k >= c2start, k >= e2start);
        if constexpr (NREM >= 2) {
            float A1c1[3];
            s1_group<3>(xv, w1, B1, A1c1, c0);
            emit_e<P2_1>(A1p[1], A1p[2], A1c0, c0, fe, w2, B2,
                         A2a, A2b, A2c, A2cur, op,
                         k + 1 >= c2start, k + 1 >= e2start);
        }
    }
    if constexpr (SEG == 2) {
        float ez[3] = {0.f, 0.f, 0.f};
        s2_step<0>(fe, ez, w2, B2, A2a, A2b, A2c, A2cur, op, true, true);
    }
}

// ---------------------------------------------------------------------------
// GEMM-tile device body (split-K, f32 atomic accumulate; out pre-seeded).
// ---------------------------------------------------------------------------
template<int RELU_A>
__device__ __forceinline__ void gemm_tile(
    const float* __restrict__ A, const float* __restrict__ Wt,
    float* __restrict__ out, int K, int N, int lda, int ldo, int kchunk,
    int bx, int by, int bz)
{
    __shared__ float As[32][36];
    __shared__ float Bs[32][36];

    int tid = threadIdx.x;
    int ty  = tid >> 3;
    int tx4 = (tid & 7) * 4;
    int c0 = bx * 32;
    int m0 = by * 32;
    int k0 = bz * kchunk;
    int klim = min(K, k0 + kchunk);

    float4 acc = make_float4(0.f, 0.f, 0.f, 0.f);

    for (int kb = k0; kb < klim; kb += 32) {
#pragma unroll
        for (int j = 0; j < 4; ++j) {
            int kk = kb + tx4 + j;
            float v = (kk < klim) ? A[(long)(m0 + ty) * lda + kk] : 0.f;
            if (RELU_A) v = fmaxf(v, 0.f);
            As[ty][tx4 + j] = v;
        }
#pragma unroll
        for (int j = 0; j < 4; ++j) {
            int kk = kb + ty;
            int c = c0 + tx4 + j;
            Bs[ty][tx4 + j] = (kk < klim && c < N) ? Wt[(long)kk * N + c] : 0.f;
        }
        __syncthreads();
#pragma unroll
        for (int kk = 0; kk < 32; ++kk) {
            float a = As[ty][kk];
            float4 bv = *(const float4*)&Bs[kk][tx4];
            acc.x = fmaf(a, bv.x, acc.x);
            acc.y = fmaf(a, bv.y, acc.y);
            acc.z = fmaf(a, bv.z, acc.z);
            acc.w = fmaf(a, bv.w, acc.w);
        }
        __syncthreads();
    }

    long m = m0 + ty;
    if (c0 + tx4 + 0 < N) atomicAdd(&out[m * ldo + c0 + tx4 + 0], acc.x);
    if (c0 + tx4 + 1 < N) atomicAdd(&out[m * ldo + c0 + tx4 + 1], acc.y);
    if (c0 + tx4 + 2 < N) atomicAdd(&out[m * ldo + c0 + tx4 + 2], acc.z);
    if (c0 + tx4 + 3 < N) atomicAdd(&out[m * ldo + c0 + tx4 + 3], acc.w);
}

// standalone split-K GEMM kernel
template<int RELU_A>
__global__ __launch_bounds__(256)
void gemm_atomic(const float* __restrict__ A, const float* __restrict__ Wt,
                 float* __restrict__ out, int K, int N, int lda, int ldo, int kchunk)
{
    gemm_tile<RELU_A>(A, Wt, out, K, N, lda, ldo, kchunk,
                      blockIdx.x, blockIdx.y, blockIdx.z);
}

// ---------------------------------------------------------------------------
// D1: conv_s12 (1197 conv blocks: seg = blk/399) ∥ lW1 GEMM (1056 blocks)
// ---------------------------------------------------------------------------
__global__ __launch_bounds__(256)
void d1_conv_s12_lw1(const float* __restrict__ x,
                     const float* __restrict__ W1, const float* __restrict__ b1,
                     const float* __restrict__ W2, const float* __restrict__ b2,
                     float* __restrict__ h2,
                     const float* __restrict__ x2, const float* __restrict__ lW1,
                     float* __restrict__ e1)
{
    int blk = blockIdx.x;
    if (blk < 1197) {
        int seg = blk / 399;
        int bx  = blk - seg * 399;
        int gid = bx * 256 + threadIdx.x;      // 399*256 == BB*PP exactly
        int b = gid / PP;
        int p = gid - b * PP;
        if (seg == 0)      s12_body<0>(x, W1, b1, W2, b2, h2, b, p);
        else if (seg == 1) s12_body<1>(x, W1, b1, W2, b2, h2, b, p);
        else               s12_body<2>(x, W1, b1, W2, b2, h2, b, p);
    } else {
        int g = blk - 1197;                     // lW1: 22 x 8 x 6
        int gx = g % 22;
        int gy = (g / 22) % 8;
        int gz = g / 176;
        gemm_tile<0>(x2, lW1, e1, 1307, 700, 1307, 700, 256, gx, gy, gz);
    }
}

// ---------------------------------------------------------------------------
// Single-stream stage machine for the small s3+s4 chain.
// ---------------------------------------------------------------------------
template<int CIN>
struct Stage {
    float w[3][CIN][5];
    float b[3];
    float xw[CIN][5];
    float m1[3], m2[3], m3[3];
    int nin;
};

__device__ __forceinline__ void init_s3(Stage<3>& s, const float* __restrict__ Wt,
                                        const float* __restrict__ Bs, int p) {
    const float* wp = Wt + (long)p * 45;
#pragma unroll
    for (int co = 0; co < 3; ++co)
#pragma unroll
        for (int ci = 0; ci < 3; ++ci)
#pragma unroll
            for (int k = 0; k < 5; ++k)
                s.w[co][ci][k] = wp[(co * 3 + ci) * 5 + k];
#pragma unroll
    for (int co = 0; co < 3; ++co) s.b[co] = Bs[(long)p * 3 + co];
#pragma unroll
    for (int ci = 0; ci < 3; ++ci)
#pragma unroll
        for (int k = 0; k < 5; ++k) s.xw[ci][k] = 0.f;
#pragma unroll
    for (int co = 0; co < 3; ++co) { s.m1[co] = -1e30f; s.m2[co] = -1e30f; s.m3[co] = -1e30f; }
    s.nin = 0;
}

template<int CIN>
__device__ __forceinline__ bool feed(Stage<CIN>& s, const float* in, float* out) {
#pragma unroll
    for (int ci = 0; ci < CIN; ++ci) {
        s.xw[ci][0] = s.xw[ci][1];
        s.xw[ci][1] = s.xw[ci][2];
        s.xw[ci][2] = s.xw[ci][3];
        s.xw[ci][3] = s.xw[ci][4];
        s.xw[ci][4] = in[ci];
    }
    int t = s.nin - 2;
    s.nin++;
    if (t < 0) return false;

    float c[3];
#pragma unroll
    for (int co = 0; co < 3; ++co) {
        float a = s.b[co];
#pragma unroll
        for (int ci = 0; ci < CIN; ++ci)
#pragma unroll
            for (int k = 0; k < 5; ++k)
                a = fmaf(s.xw[ci][k], s.w[co][ci][k], a);
        c[co] = fmaxf(a, 0.f);
    }

    bool emit = false;
    int ph = t % 3;
    if (ph == 0) {
        if (t >= 9) {
#pragma unroll
            for (int co = 0; co < 3; ++co) out[co] = fmaxf(s.m1[co], c[co]);
            emit = true;
        }
#pragma unroll
        for (int co = 0; co < 3; ++co) {
            float a = fmaxf(s.m2[co], c[co]);
            float bb = fmaxf(s.m3[co], c[co]);
            s.m1[co] = a; s.m2[co] = bb; s.m3[co] = c[co];
        }
    } else {
#pragma unroll
        for (int co = 0; co < 3; ++co) {
            s.m1[co] = fmaxf(s.m1[co], c[co]);
            s.m2[co] = fmaxf(s.m2[co], c[co]);
            s.m3[co] = fmaxf(s.m3[co], c[co]);
        }
    }
    return emit;
}

__device__ __forceinline__ void s34_body(
    const float* __restrict__ h2,
    const float* __restrict__ W3, const float* __restrict__ b3,
    const float* __restrict__ W4, const float* __restrict__ b4,
    float* __restrict__ cbuf, int b, int p)
{
    Stage<3> s3, s4;
    init_s3(s3, W3, b3, p);
    init_s3(s4, W4, b4, p);

    const float* inp = h2 + (long)b * 37 * 3 * PP + p;
    float* o4 = cbuf + (long)b * 1297 + p;

    float v3[3], v4[3];
    float z[3] = {0.f, 0.f, 0.f};

    float r0[3], r1[3], r2[3], r3[3], r4[3];
#pragma unroll
    for (int ci = 0; ci < 3; ++ci) {
        r0[ci] = inp[(long)(0 * 3 + ci) * PP];
        r1[ci] = inp[(long)(1 * 3 + ci) * PP];
        r2[ci] = inp[(long)(2 * 3 + ci) * PP];
        r3[ci] = inp[(long)(3 * 3 + ci) * PP];
        r4[ci] = inp[(long)(4 * 3 + ci) * PP];
    }

    for (int i = 0; i < 39; ++i) {
        float nn[3];
        int i5 = i + 5;
#pragma unroll
        for (int ci = 0; ci < 3; ++ci)
            nn[ci] = (i5 < 37) ? inp[(long)(i5 * 3 + ci) * PP] : 0.f;
        if (feed(s3, r0, v3)) {
            if (feed(s4, v3, v4)) {
#pragma unroll
                for (int co = 0; co < 3; ++co) o4[co * PP] = v4[co];
            }
        }
#pragma unroll
        for (int ci = 0; ci < 3; ++ci) {
            r0[ci] = r1[ci]; r1[ci] = r2[ci]; r2[ci] = r3[ci]; r3[ci] = r4[ci]; r4[ci] = nn[ci];
        }
    }
    for (int r = 0; r < 2; ++r) {
        if (feed(s4, z, v4)) {
#pragma unroll
            for (int co = 0; co < 3; ++co) o4[co * PP] = v4[co];
        }
    }
}

// ---------------------------------------------------------------------------
// D2: conv_s34 (399 blocks) ∥ lW2 GEMM (336 blocks)
// ---------------------------------------------------------------------------
__global__ __launch_bounds__(256)
void d2_conv_s34_lw2(const float* __restrict__ h2,
                     const float* __restrict__ W3, const float* __restrict__ b3,
                     const float* __restrict__ W4, const float* __restrict__ b4,
                     float* __restrict__ cbuf,
                     const float* __restrict__ e1, const float* __restrict__ lW2,
                     float* __restrict__ e2)
{
    int blk = blockIdx.x;
    if (blk < 399) {
        int gid = blk * 256 + threadIdx.x;
        int b = gid / PP;
        int p = gid - b * PP;
        s34_body(h2, W3, b3, W4, b4, cbuf, b, p);
    } else {
        int g = blk - 399;                      // lW2: 7 x 8 x 6, kchunk 128
        int gx = g % 7;
        int gy = (g / 7) % 8;
        int gz = g / 56;
        gemm_tile<1>(e1, lW2, e2, 700, 200, 700, 200, 128, gx, gy, gz);
    }
}

__global__ __launch_bounds__(256)
void init_bias(float* __restrict__ e1, const float* __restrict__ lb1,
               float* __restrict__ e2, const float* __restrict__ lb2,
               float* __restrict__ enc2, const float* __restrict__ lb3,
               float* __restrict__ c1, const float* __restrict__ cb1,
               float* __restrict__ c2, const float* __restrict__ cb2,
               float* __restrict__ c3, const float* __restrict__ cb3)
{
    int idx = blockIdx.x * 256 + threadIdx.x;
    if (idx < BB * 700) { e1[idx] = lb1[idx % 700]; return; }
    idx -= BB * 700;
    if (idx < BB * 200) { e2[idx] = lb2[idx % 200]; return; }
    idx -= BB * 200;
    if (idx < BB * 100) { int m = idx / 100, c = idx % 100; enc2[(long)m * 1297 + c] = lb3[c]; return; }
    idx -= BB * 100;
    if (idx < BB * 500) { c1[idx] = cb1[idx % 500]; return; }
    idx -= BB * 500;
    if (idx < BB * 100) { c2[idx] = cb2[idx % 100]; return; }
    idx -= BB * 100;
    if (idx < BB * 20)  { c3[idx] = cb3[idx % 20]; return; }
}

__global__ __launch_bounds__(64)
void final_kernel(const float* __restrict__ c3,
                  const float* __restrict__ fW,
                  const float* __restrict__ fb,
                  float* __restrict__ out)
{
    int m = blockIdx.x * 64 + threadIdx.x;
    if (m >= BB) return;
    float acc = fb[0];
#pragma unroll
    for (int k = 0; k < 20; ++k)
        acc = fmaf(fmaxf(c3[m * 20 + k], 0.f), fW[k], acc);
    out[m] = acc;
}

extern "C" void kernel_launch(void* const* d_in, const int* in_sizes, int n_in,
                              void* d_out, int out_size, void* d_ws, size_t ws_size,
                              hipStream_t stream)
{
    const float* x   = (const float*)d_in[0];
    const float* x2  = (const float*)d_in[1];
    const float* W1  = (const float*)d_in[2];
    const float* b1  = (const float*)d_in[3];
    const float* W2  = (const float*)d_in[4];
    const float* b2  = (const float*)d_in[5];
    const float* W3  = (const float*)d_in[6];
    const float* b3  = (const float*)d_in[7];
    const float* W4  = (const float*)d_in[8];
    const float* b4  = (const float*)d_in[9];
    const float* lW1 = (const float*)d_in[10];
    const float* lb1 = (const float*)d_in[11];
    const float* lW2 = (const float*)d_in[12];
    const float* lb2 = (const float*)d_in[13];
    const float* lW3 = (const float*)d_in[14];
    const float* lb3 = (const float*)d_in[15];
    const float* cW1 = (const float*)d_in[16];
    const float* cb1 = (const float*)d_in[17];
    const float* cW2 = (const float*)d_in[18];
    const float* cb2 = (const float*)d_in[19];
    const float* cW3 = (const float*)d_in[20];
    const float* cb3 = (const float*)d_in[21];
    const float* fW  = (const float*)d_in[22];
    const float* fb  = (const float*)d_in[23];
    float* out = (float*)d_out;

    float* ws = (float*)d_ws;
    const long n_h2   = (long)BB * 37 * 3 * PP;
    const long n_cbuf = (long)BB * 1297;
    float* h2   = ws;
    float* cbuf = h2 + n_h2;
    float* e1   = cbuf + n_cbuf;
    float* e2   = e1 + (long)BB * 700;
    float* c1   = e2 + (long)BB * 200;
    float* c2   = c1 + (long)BB * 500;
    float* c3b  = c2 + (long)BB * 100;

    init_bias<<<1620, 256, 0, stream>>>(e1, lb1, e2, lb2, cbuf + 1197, lb3,
                                        c1, cb1, c2, cb2, c3b, cb3);

    // D1: conv s1+s2 (3 segs) ∥ lW1 GEMM
    d1_conv_s12_lw1<<<1197 + 1056, 256, 0, stream>>>(x, W1, b1, W2, b2, h2,
                                                     x2, lW1, e1);
    // D2: conv s3+s4 ∥ lW2 GEMM
    d2_conv_s34_lw2<<<399 + 336, 256, 0, stream>>>(h2, W3, b3, W4, b4, cbuf,
                                                   e1, lW2, e2);
    // lW3 -> cbuf[:,1197:1297]
    gemm_atomic<1><<<dim3(4, 8, 4), 256, 0, stream>>>(e2, lW3, cbuf + 1197, 200, 100, 200, 1297, 64);

    // combined head
    gemm_atomic<0><<<dim3(16, 8, 6), 256, 0, stream>>>(cbuf, cW1, c1, 1297, 500, 1297, 500, 256);
    gemm_atomic<1><<<dim3( 4, 8, 8), 256, 0, stream>>>(c1, cW2, c2, 500, 100, 500, 100, 64);
    gemm_atomic<1><<<dim3( 1, 8, 4), 256, 0, stream>>>(c2, cW3, c3b, 100, 20, 100, 20, 32);

    final_kernel<<<dim3(4), 64, 0, stream>>>(c3b, fW, fb, out);
}